// Round 4
// baseline (440.486 us; speedup 1.0000x reference)
//
#include <hip/hip_runtime.h>
#include <hip/hip_bf16.h>

// RetinaNet focal classification loss, MI355X. Output: scalar f32.
//
// Round-4: division-free threshold math (iou>=0.5 <=> 3*inter >= area_a+ga;
// iou<0.4 <=> 3.5*inter < area_a+ga) -> 13 VALU ops per anchor-gt pair on the
// fast path (all gt labels == 0, detected per image via __ballot). Exact
// argmax/label slow path kept for generality. 1568 blocks (98x16), 2 tiles of
// APT=4 each -> 6272 waves, fully co-resident in one dispatch round.
//
// ws: 32 floats: [0..15] per-image loss sums, [16..31] per-image pos counts
// (zeroed by hipMemsetAsync each launch; atomically accumulated by rnl_main).

#define A_N 200000
#define B_N 16
#define G_N 32
#define APT 4
#define BLK 256
#define TILE (BLK * APT)          // 1024
#define TPB 2                     // tiles per block
#define SPAN (TILE * TPB)         // 2048
#define NBX ((A_N + SPAN - 1) / SPAN)   // 98

#define C_POS (0.25f * 0.69314718f)     // alpha * ln2   (log2 -> ln fold)
#define C_NEG (0.75f * 0.69314718f)     // (1-alpha) * ln2

__launch_bounds__(BLK, 8)
__global__ void rnl_main(const float4* __restrict__ anchors,
                         const float* __restrict__ probs,
                         const float* __restrict__ y_true,
                         float* __restrict__ ws) {
    // gt entry j: {x1,y1,x2,y2, -ga, 0, ga, lab}
    __shared__ float sgt[G_N * 8];
    __shared__ float sraw[G_N * 5];
    __shared__ int   sflag;

    const int b = blockIdx.y;
    const int t = threadIdx.x;

    if (t < G_N * 5) sraw[t] = y_true[b * (G_N * 5) + t];
    __syncthreads();
    if (t < 64) {                          // wave 0 builds gt table + flag
        float lb = 0.0f;
        if (t < G_N) {
            float cx = sraw[t * 5 + 0], cy = sraw[t * 5 + 1];
            float w  = sraw[t * 5 + 2], h  = sraw[t * 5 + 3];
            lb = sraw[t * 5 + 4];
            float x1 = cx - 0.5f * w, y1 = cy - 0.5f * h;
            float x2 = cx + 0.5f * w, y2 = cy + 0.5f * h;
            float ga = (x2 - x1) * (y2 - y1);
            float* e = &sgt[t * 8];
            e[0] = x1; e[1] = y1; e[2] = x2; e[3] = y2;
            e[4] = -ga; e[5] = 0.0f; e[6] = ga; e[7] = lb;
        }
        unsigned long long bal = __ballot(lb != 0.0f);
        if (t == 0) sflag = (bal == 0ULL) ? 1 : 0;
    }
    __syncthreads();

    const bool fast = (sflag != 0);        // block-uniform branch
    const float lab0 = sgt[7];

    float loss = 0.0f, cnt = 0.0f;

    #pragma unroll 1
    for (int tt = 0; tt < TPB; ++tt) {
        const int base = blockIdx.x * SPAN + tt * TILE + t;

        float ax[APT], ay[APT], az[APT], aw[APT], sa[APT], pv[APT], vm[APT];
        #pragma unroll
        for (int k = 0; k < APT; ++k) {
            int idx  = base + k * BLK;
            int idxc = idx < A_N ? idx : A_N - 1;
            vm[k] = idx < A_N ? 1.0f : 0.0f;
            float4 an = anchors[idxc];
            ax[k] = an.x; ay[k] = an.y; az[k] = an.z; aw[k] = an.w;
            sa[k] = (an.z - an.x) * (an.w - an.y) + 1e-8f;   // area_a + ref eps
            pv[k] = probs[b * A_N + idxc];
        }

        if (fast) {
            // ---- fast path: all labels zero -> predicates only, 13 ops/pair
            float m1[APT], m2[APT];
            #pragma unroll
            for (int k = 0; k < APT; ++k) { m1[k] = -1e30f; m2[k] = -1e30f; }

            #pragma unroll
            for (int j = 0; j < G_N; ++j) {
                float4 gb = *reinterpret_cast<const float4*>(&sgt[j * 8]);
                float nga = sgt[j * 8 + 4];
                #pragma unroll
                for (int k = 0; k < APT; ++k) {
                    float ltx = fmaxf(ax[k], gb.x);
                    float lty = fmaxf(ay[k], gb.y);
                    float rbx = fminf(az[k], gb.z);
                    float rby = fminf(aw[k], gb.w);
                    float iw  = fmaxf(rbx - ltx, 0.0f);
                    float ih  = fmaxf(rby - lty, 0.0f);
                    float inter = iw * ih;
                    m1[k] = fmaxf(m1[k], fmaf(inter, 3.0f, nga));
                    m2[k] = fmaxf(m2[k], fmaf(inter, 3.5f, nga));
                }
            }
            #pragma unroll
            for (int k = 0; k < APT; ++k) {
                bool pos = m1[k] >= sa[k];          // max iou >= 0.5
                bool neg = m2[k] <  sa[k];          // max iou <  0.4
                float p = __builtin_amdgcn_fmed3f(pv[k], 1e-7f, 1.0f - 1e-7f);
                float q = 1.0f - p;
                float x = pos ? p : q;
                float w = pos ? C_POS * q * q : C_NEG * p * p;
                float l = w * (-__log2f(x));
                l = (pos | neg) ? l : 0.0f;
                loss += vm[k] * l;
                cnt  += pos ? vm[k] : 0.0f;
            }
        } else {
            // ---- slow path: exact argmax + label (general correctness)
            float bi[APT], bS[APT], bl[APT];
            #pragma unroll
            for (int k = 0; k < APT; ++k) { bi[k] = 0.0f; bS[k] = 1.0f; bl[k] = lab0; }

            #pragma unroll
            for (int j = 0; j < G_N; ++j) {
                float4 gb = *reinterpret_cast<const float4*>(&sgt[j * 8]);
                float2 gl = *reinterpret_cast<const float2*>(&sgt[j * 8 + 6]); // {ga,lab}
                #pragma unroll
                for (int k = 0; k < APT; ++k) {
                    float ltx = fmaxf(ax[k], gb.x);
                    float lty = fmaxf(ay[k], gb.y);
                    float rbx = fminf(az[k], gb.z);
                    float rby = fminf(aw[k], gb.w);
                    float iw  = fmaxf(rbx - ltx, 0.0f);
                    float ih  = fmaxf(rby - lty, 0.0f);
                    float inter = iw * ih;
                    float S = sa[k] + gl.x;
                    // iou_j > iou_best <=> inter_j*S_b > inter_b*S_j (uni>0; inter terms cancel)
                    bool better = inter * bS[k] > bi[k] * S;
                    bi[k] = better ? inter : bi[k];
                    bS[k] = better ? S     : bS[k];
                    bl[k] = better ? gl.y  : bl[k];
                }
            }
            #pragma unroll
            for (int k = 0; k < APT; ++k) {
                bool pos = 3.0f * bi[k] >= bS[k];   // max iou >= 0.5
                bool neg = 3.5f * bi[k] <  bS[k];   // max iou <  0.4
                bool tp  = pos && (bl[k] == 0.0f);  // one_hot(assigned, C=1) hit
                float p = __builtin_amdgcn_fmed3f(pv[k], 1e-7f, 1.0f - 1e-7f);
                float q = 1.0f - p;
                float x = tp ? p : q;
                float w = tp ? C_POS * q * q : C_NEG * p * p;
                float l = w * (-__log2f(x));
                l = (pos | neg) ? l : 0.0f;
                loss += vm[k] * l;
                cnt  += pos ? vm[k] : 0.0f;
            }
        }
    }

    // block reduction: wave shuffle, then cross-wave via LDS, 2 atomics/block
    #pragma unroll
    for (int off = 32; off > 0; off >>= 1) {
        loss += __shfl_down(loss, off);
        cnt  += __shfl_down(cnt, off);
    }
    __shared__ float s_l[4], s_c[4];
    int wid  = t >> 6;
    int lane = t & 63;
    if (lane == 0) { s_l[wid] = loss; s_c[wid] = cnt; }
    __syncthreads();
    if (t == 0) {
        atomicAdd(&ws[b],       s_l[0] + s_l[1] + s_l[2] + s_l[3]);
        atomicAdd(&ws[B_N + b], s_c[0] + s_c[1] + s_c[2] + s_c[3]);
    }
}

__global__ void rnl_final(const float* __restrict__ ws, float* __restrict__ out) {
    if (threadIdx.x == 0) {
        float s = 0.0f;
        #pragma unroll
        for (int b = 0; b < B_N; ++b) {
            s += ws[b] / fmaxf(ws[B_N + b], 1.0f);
        }
        out[0] = s * (1.0f / (float)B_N);
    }
}

extern "C" void kernel_launch(void* const* d_in, const int* in_sizes, int n_in,
                              void* d_out, int out_size, void* d_ws, size_t ws_size,
                              hipStream_t stream) {
    const float* y_true     = (const float*)d_in[0];
    const float* y_classifs = (const float*)d_in[1];
    // d_in[2] = y_regressions: unused by the loss
    const float* anchors    = (const float*)d_in[3];
    float* ws = (float*)d_ws;

    hipMemsetAsync(ws, 0, 2 * B_N * sizeof(float), stream);  // capturable memset node

    dim3 grid(NBX, B_N);
    rnl_main<<<grid, BLK, 0, stream>>>((const float4*)anchors, y_classifs,
                                       y_true, ws);

    rnl_final<<<1, 64, 0, stream>>>(ws, (float*)d_out);
}

// Round 5
// 315.760 us; speedup vs baseline: 1.3950x; 1.3950x over previous
//
#include <hip/hip_runtime.h>
#include <hip/hip_bf16.h>

// RetinaNet focal classification loss, MI355X. Output: scalar f32.
//
// Round-5 = round-4 structure with the spill fixed: __launch_bounds__(256,4)
// (128-VGPR cap) instead of (256,8) (64-VGPR cap, which spilled ~250 B/thread
// to scratch -> 1.46 GB HBM traffic -> 440 us).
//
// Fast path (all gt labels == 0, detected via __ballot): division-free
// predicates  iou>=0.5 <=> 3*inter >= area_a+ga ;  iou<0.4 <=> 3.5*inter <
// area_a+ga  -> 13 VALU ops per anchor-gt pair, no argmax. Exact argmax/label
// slow path kept for generality. 98x16 blocks, 2 tiles of APT=4 each -> 6272
// waves, one dispatch round.
//
// ws: 32 floats: [0..15] per-image loss sums, [16..31] per-image pos counts.

#define A_N 200000
#define B_N 16
#define G_N 32
#define APT 4
#define BLK 256
#define TILE (BLK * APT)          // 1024
#define TPB 2                     // tiles per block
#define SPAN (TILE * TPB)         // 2048
#define NBX ((A_N + SPAN - 1) / SPAN)   // 98

#define C_POS (0.25f * 0.69314718f)     // alpha * ln2   (log2 -> ln fold)
#define C_NEG (0.75f * 0.69314718f)     // (1-alpha) * ln2

__launch_bounds__(BLK, 4)
__global__ void rnl_main(const float4* __restrict__ anchors,
                         const float* __restrict__ probs,
                         const float* __restrict__ y_true,
                         float* __restrict__ ws) {
    // gt entry j: {x1,y1,x2,y2, -ga, 0, ga, lab}
    __shared__ float sgt[G_N * 8];
    __shared__ float sraw[G_N * 5];
    __shared__ int   sflag;

    const int b = blockIdx.y;
    const int t = threadIdx.x;

    if (t < G_N * 5) sraw[t] = y_true[b * (G_N * 5) + t];
    __syncthreads();
    if (t < 64) {                          // wave 0 builds gt table + flag
        float lb = 0.0f;
        if (t < G_N) {
            float cx = sraw[t * 5 + 0], cy = sraw[t * 5 + 1];
            float w  = sraw[t * 5 + 2], h  = sraw[t * 5 + 3];
            lb = sraw[t * 5 + 4];
            float x1 = cx - 0.5f * w, y1 = cy - 0.5f * h;
            float x2 = cx + 0.5f * w, y2 = cy + 0.5f * h;
            float ga = (x2 - x1) * (y2 - y1);
            float* e = &sgt[t * 8];
            e[0] = x1; e[1] = y1; e[2] = x2; e[3] = y2;
            e[4] = -ga; e[5] = 0.0f; e[6] = ga; e[7] = lb;
        }
        unsigned long long bal = __ballot(lb != 0.0f);
        if (t == 0) sflag = (bal == 0ULL) ? 1 : 0;
    }
    __syncthreads();

    const bool fast = (sflag != 0);        // block-uniform branch
    const float lab0 = sgt[7];

    float loss = 0.0f, cnt = 0.0f;

    #pragma unroll 1
    for (int tt = 0; tt < TPB; ++tt) {
        const int base = blockIdx.x * SPAN + tt * TILE + t;

        float ax[APT], ay[APT], az[APT], aw[APT], sa[APT], pv[APT], vm[APT];
        #pragma unroll
        for (int k = 0; k < APT; ++k) {
            int idx  = base + k * BLK;
            int idxc = idx < A_N ? idx : A_N - 1;
            vm[k] = idx < A_N ? 1.0f : 0.0f;
            float4 an = anchors[idxc];
            ax[k] = an.x; ay[k] = an.y; az[k] = an.z; aw[k] = an.w;
            sa[k] = (an.z - an.x) * (an.w - an.y) + 1e-8f;   // area_a + ref eps
            pv[k] = probs[b * A_N + idxc];
        }

        if (fast) {
            // ---- fast path: all labels zero -> predicates only, 13 ops/pair
            float m1[APT], m2[APT];
            #pragma unroll
            for (int k = 0; k < APT; ++k) { m1[k] = -1e30f; m2[k] = -1e30f; }

            #pragma unroll
            for (int j = 0; j < G_N; ++j) {
                float4 gb = *reinterpret_cast<const float4*>(&sgt[j * 8]);
                float nga = sgt[j * 8 + 4];
                #pragma unroll
                for (int k = 0; k < APT; ++k) {
                    float ltx = fmaxf(ax[k], gb.x);
                    float lty = fmaxf(ay[k], gb.y);
                    float rbx = fminf(az[k], gb.z);
                    float rby = fminf(aw[k], gb.w);
                    float iw  = fmaxf(rbx - ltx, 0.0f);
                    float ih  = fmaxf(rby - lty, 0.0f);
                    float inter = iw * ih;
                    m1[k] = fmaxf(m1[k], fmaf(inter, 3.0f, nga));
                    m2[k] = fmaxf(m2[k], fmaf(inter, 3.5f, nga));
                }
            }
            #pragma unroll
            for (int k = 0; k < APT; ++k) {
                bool pos = m1[k] >= sa[k];          // max iou >= 0.5
                bool neg = m2[k] <  sa[k];          // max iou <  0.4
                float p = __builtin_amdgcn_fmed3f(pv[k], 1e-7f, 1.0f - 1e-7f);
                float q = 1.0f - p;
                float x = pos ? p : q;
                float w = pos ? C_POS * q * q : C_NEG * p * p;
                float l = w * (-__log2f(x));
                l = (pos | neg) ? l : 0.0f;
                loss += vm[k] * l;
                cnt  += pos ? vm[k] : 0.0f;
            }
        } else {
            // ---- slow path: exact argmax + label (general correctness)
            float bi[APT], bS[APT], bl[APT];
            #pragma unroll
            for (int k = 0; k < APT; ++k) { bi[k] = 0.0f; bS[k] = 1.0f; bl[k] = lab0; }

            #pragma unroll
            for (int j = 0; j < G_N; ++j) {
                float4 gb = *reinterpret_cast<const float4*>(&sgt[j * 8]);
                float2 gl = *reinterpret_cast<const float2*>(&sgt[j * 8 + 6]); // {ga,lab}
                #pragma unroll
                for (int k = 0; k < APT; ++k) {
                    float ltx = fmaxf(ax[k], gb.x);
                    float lty = fmaxf(ay[k], gb.y);
                    float rbx = fminf(az[k], gb.z);
                    float rby = fminf(aw[k], gb.w);
                    float iw  = fmaxf(rbx - ltx, 0.0f);
                    float ih  = fmaxf(rby - lty, 0.0f);
                    float inter = iw * ih;
                    float S = sa[k] + gl.x;
                    // iou_j > iou_best <=> inter_j*S_b > inter_b*S_j
                    bool better = inter * bS[k] > bi[k] * S;
                    bi[k] = better ? inter : bi[k];
                    bS[k] = better ? S     : bS[k];
                    bl[k] = better ? gl.y  : bl[k];
                }
            }
            #pragma unroll
            for (int k = 0; k < APT; ++k) {
                bool pos = 3.0f * bi[k] >= bS[k];   // max iou >= 0.5
                bool neg = 3.5f * bi[k] <  bS[k];   // max iou <  0.4
                bool tp  = pos && (bl[k] == 0.0f);  // one_hot(assigned, C=1) hit
                float p = __builtin_amdgcn_fmed3f(pv[k], 1e-7f, 1.0f - 1e-7f);
                float q = 1.0f - p;
                float x = tp ? p : q;
                float w = tp ? C_POS * q * q : C_NEG * p * p;
                float l = w * (-__log2f(x));
                l = (pos | neg) ? l : 0.0f;
                loss += vm[k] * l;
                cnt  += pos ? vm[k] : 0.0f;
            }
        }
    }

    // block reduction: wave shuffle, then cross-wave via LDS, 2 atomics/block
    #pragma unroll
    for (int off = 32; off > 0; off >>= 1) {
        loss += __shfl_down(loss, off);
        cnt  += __shfl_down(cnt, off);
    }
    __shared__ float s_l[4], s_c[4];
    int wid  = t >> 6;
    int lane = t & 63;
    if (lane == 0) { s_l[wid] = loss; s_c[wid] = cnt; }
    __syncthreads();
    if (t == 0) {
        atomicAdd(&ws[b],       s_l[0] + s_l[1] + s_l[2] + s_l[3]);
        atomicAdd(&ws[B_N + b], s_c[0] + s_c[1] + s_c[2] + s_c[3]);
    }
}

__global__ void rnl_final(const float* __restrict__ ws, float* __restrict__ out) {
    if (threadIdx.x == 0) {
        float s = 0.0f;
        #pragma unroll
        for (int b = 0; b < B_N; ++b) {
            s += ws[b] / fmaxf(ws[B_N + b], 1.0f);
        }
        out[0] = s * (1.0f / (float)B_N);
    }
}

extern "C" void kernel_launch(void* const* d_in, const int* in_sizes, int n_in,
                              void* d_out, int out_size, void* d_ws, size_t ws_size,
                              hipStream_t stream) {
    const float* y_true     = (const float*)d_in[0];
    const float* y_classifs = (const float*)d_in[1];
    // d_in[2] = y_regressions: unused by the loss
    const float* anchors    = (const float*)d_in[3];
    float* ws = (float*)d_ws;

    hipMemsetAsync(ws, 0, 2 * B_N * sizeof(float), stream);  // capturable memset node

    dim3 grid(NBX, B_N);
    rnl_main<<<grid, BLK, 0, stream>>>((const float4*)anchors, y_classifs,
                                       y_true, ws);

    rnl_final<<<1, 64, 0, stream>>>(ws, (float*)d_out);
}

// Round 6
// 60.550 us; speedup vs baseline: 7.2747x; 5.2149x over previous
//
#include <hip/hip_runtime.h>
#include <hip/hip_bf16.h>

// RetinaNet focal classification loss, MI355X. Output: scalar f32.
//
// Round-6: round-4's math in round-3's spill-free shell.
// The r4/r5 spill (0.6-1.5 GB scratch traffic) came from the outer
// `#pragma unroll 1` tile loop: LICM hoisted ~380 loop-invariant LDS gt
// values across two fully-unrolled j-loops -> live-set explosion -> spill.
// Fix: NO outer loop (one tile of APT=4 per block, grid 196x16, like r3 which
// ran at 32 VGPR / zero spill), and no min-waves launch_bounds cap.
//
// Fast path (all gt labels == 0, detected on-device via __ballot -> generic):
// division-free predicates  iou>=0.5 <=> fma(inter,3,-ga) >= area_a+eps ;
// iou<0.4 <=> fma(inter,3.5,-ga) < area_a+eps  -> 13 VALU ops/pair, and the
// max-trackers are independent fmax chains (no cmp->cndmask serial chain).
// Slow path: exact cross-multiplication argmax (r3 logic).
//
// ws: 32 floats: [0..15] per-image loss sums, [16..31] per-image pos counts.

#define A_N 200000
#define B_N 16
#define G_N 32
#define APT 4
#define BLK 256
#define TILE (BLK * APT)                 // 1024
#define NBX ((A_N + TILE - 1) / TILE)    // 196

#define C_POS (0.25f * 0.69314718f)      // alpha * ln2   (log2 -> ln fold)
#define C_NEG (0.75f * 0.69314718f)      // (1-alpha) * ln2

__launch_bounds__(BLK)
__global__ void rnl_main(const float4* __restrict__ anchors,
                         const float* __restrict__ probs,
                         const float* __restrict__ y_true,
                         float* __restrict__ ws) {
    // gt entry j: {x1,y1,x2,y2, -ga, ga, lab, pad}
    __shared__ float sgt[G_N * 8];
    __shared__ float sraw[G_N * 5];
    __shared__ int   sflag;

    const int b = blockIdx.y;
    const int t = threadIdx.x;

    if (t < G_N * 5) sraw[t] = y_true[b * (G_N * 5) + t];
    __syncthreads();
    if (t < 64) {                          // wave 0 builds gt table + flag
        float lb = 0.0f;
        if (t < G_N) {
            float cx = sraw[t * 5 + 0], cy = sraw[t * 5 + 1];
            float w  = sraw[t * 5 + 2], h  = sraw[t * 5 + 3];
            lb = sraw[t * 5 + 4];
            float x1 = cx - 0.5f * w, y1 = cy - 0.5f * h;
            float x2 = cx + 0.5f * w, y2 = cy + 0.5f * h;
            float ga = (x2 - x1) * (y2 - y1);
            float* e = &sgt[t * 8];
            e[0] = x1; e[1] = y1; e[2] = x2; e[3] = y2;
            e[4] = -ga; e[5] = ga; e[6] = lb; e[7] = 0.0f;
        }
        unsigned long long bal = __ballot(lb != 0.0f);
        if (t == 0) sflag = (bal == 0ULL) ? 1 : 0;
    }
    __syncthreads();

    const int base = blockIdx.x * TILE + t;
    const float lab0 = sgt[6];

    float loss = 0.0f, cnt = 0.0f;

    float ax[APT], ay[APT], az[APT], aw[APT], sa[APT], pv[APT], vm[APT];
    #pragma unroll
    for (int k = 0; k < APT; ++k) {
        int idx  = base + k * BLK;
        int idxc = idx < A_N ? idx : A_N - 1;
        vm[k] = idx < A_N ? 1.0f : 0.0f;
        float4 an = anchors[idxc];
        ax[k] = an.x; ay[k] = an.y; az[k] = an.z; aw[k] = an.w;
        sa[k] = (an.z - an.x) * (an.w - an.y) + 1e-8f;   // area_a + ref eps
        pv[k] = probs[b * A_N + idxc];
    }

    if (sflag) {
        // ---- fast path: all labels zero -> 13 ops/pair, fmax-chain trackers
        float m1[APT], m2[APT];
        #pragma unroll
        for (int k = 0; k < APT; ++k) { m1[k] = -1e30f; m2[k] = -1e30f; }

        #pragma unroll
        for (int j = 0; j < G_N; ++j) {
            float4 gb = *reinterpret_cast<const float4*>(&sgt[j * 8]);
            float nga = sgt[j * 8 + 4];
            #pragma unroll
            for (int k = 0; k < APT; ++k) {
                float ltx = fmaxf(ax[k], gb.x);
                float lty = fmaxf(ay[k], gb.y);
                float rbx = fminf(az[k], gb.z);
                float rby = fminf(aw[k], gb.w);
                float iw  = fmaxf(rbx - ltx, 0.0f);
                float ih  = fmaxf(rby - lty, 0.0f);
                float inter = iw * ih;
                m1[k] = fmaxf(m1[k], fmaf(inter, 3.0f, nga));
                m2[k] = fmaxf(m2[k], fmaf(inter, 3.5f, nga));
            }
        }
        #pragma unroll
        for (int k = 0; k < APT; ++k) {
            bool pos = m1[k] >= sa[k];          // max iou >= 0.5
            bool neg = m2[k] <  sa[k];          // max iou <  0.4
            float p = __builtin_amdgcn_fmed3f(pv[k], 1e-7f, 1.0f - 1e-7f);
            float q = 1.0f - p;
            float x = pos ? p : q;              // label==0 -> pos implies target hit
            float w = pos ? C_POS * q * q : C_NEG * p * p;
            float l = w * (-__log2f(x));
            l = (pos | neg) ? l : 0.0f;
            loss += vm[k] * l;
            cnt  += pos ? vm[k] : 0.0f;
        }
    } else {
        // ---- slow path: exact argmax + label (general correctness)
        float bi[APT], bS[APT], bl[APT];
        #pragma unroll
        for (int k = 0; k < APT; ++k) { bi[k] = 0.0f; bS[k] = 1.0f; bl[k] = lab0; }

        #pragma unroll
        for (int j = 0; j < G_N; ++j) {
            float4 gb = *reinterpret_cast<const float4*>(&sgt[j * 8]);
            float2 gl = *reinterpret_cast<const float2*>(&sgt[j * 8 + 5]); // {ga,lab}
            #pragma unroll
            for (int k = 0; k < APT; ++k) {
                float ltx = fmaxf(ax[k], gb.x);
                float lty = fmaxf(ay[k], gb.y);
                float rbx = fminf(az[k], gb.z);
                float rby = fminf(aw[k], gb.w);
                float iw  = fmaxf(rbx - ltx, 0.0f);
                float ih  = fmaxf(rby - lty, 0.0f);
                float inter = iw * ih;
                float S = sa[k] + gl.x;
                // iou_j > iou_best <=> inter_j*S_best > inter_best*S_j
                bool better = inter * bS[k] > bi[k] * S;
                bi[k] = better ? inter : bi[k];
                bS[k] = better ? S     : bS[k];
                bl[k] = better ? gl.y  : bl[k];
            }
        }
        #pragma unroll
        for (int k = 0; k < APT; ++k) {
            bool pos = 3.0f * bi[k] >= bS[k];   // max iou >= 0.5
            bool neg = 3.5f * bi[k] <  bS[k];   // max iou <  0.4
            bool tp  = pos && (bl[k] == 0.0f);  // one_hot(assigned, C=1) hit
            float p = __builtin_amdgcn_fmed3f(pv[k], 1e-7f, 1.0f - 1e-7f);
            float q = 1.0f - p;
            float x = tp ? p : q;
            float w = tp ? C_POS * q * q : C_NEG * p * p;
            float l = w * (-__log2f(x));
            l = (pos | neg) ? l : 0.0f;
            loss += vm[k] * l;
            cnt  += pos ? vm[k] : 0.0f;
        }
    }

    // block reduction: wave shuffle, then cross-wave via LDS, 2 atomics/block
    #pragma unroll
    for (int off = 32; off > 0; off >>= 1) {
        loss += __shfl_down(loss, off);
        cnt  += __shfl_down(cnt, off);
    }
    __shared__ float s_l[4], s_c[4];
    int wid  = t >> 6;
    int lane = t & 63;
    if (lane == 0) { s_l[wid] = loss; s_c[wid] = cnt; }
    __syncthreads();
    if (t == 0) {
        atomicAdd(&ws[b],       s_l[0] + s_l[1] + s_l[2] + s_l[3]);
        atomicAdd(&ws[B_N + b], s_c[0] + s_c[1] + s_c[2] + s_c[3]);
    }
}

__global__ void rnl_final(const float* __restrict__ ws, float* __restrict__ out) {
    if (threadIdx.x == 0) {
        float s = 0.0f;
        #pragma unroll
        for (int b = 0; b < B_N; ++b) {
            s += ws[b] / fmaxf(ws[B_N + b], 1.0f);
        }
        out[0] = s * (1.0f / (float)B_N);
    }
}

extern "C" void kernel_launch(void* const* d_in, const int* in_sizes, int n_in,
                              void* d_out, int out_size, void* d_ws, size_t ws_size,
                              hipStream_t stream) {
    const float* y_true     = (const float*)d_in[0];
    const float* y_classifs = (const float*)d_in[1];
    // d_in[2] = y_regressions: unused by the loss
    const float* anchors    = (const float*)d_in[3];
    float* ws = (float*)d_ws;

    hipMemsetAsync(ws, 0, 2 * B_N * sizeof(float), stream);  // capturable memset node

    dim3 grid(NBX, B_N);
    rnl_main<<<grid, BLK, 0, stream>>>((const float4*)anchors, y_classifs,
                                       y_true, ws);

    rnl_final<<<1, 64, 0, stream>>>(ws, (float*)d_out);
}

// Round 7
// 44.431 us; speedup vs baseline: 9.9140x; 1.3628x over previous
//
#include <hip/hip_runtime.h>
#include <hip/hip_bf16.h>

// RetinaNet focal classification loss, MI355X. Output: scalar f32.
//
// Round-7: APT=8 (one LDS gt read feeds 104 VALU ops, halves LDS-pipe
// pressure + latency exposure per op), grid 98x16 = 6272 waves -> single
// dispatch round (24.5 waves/CU), no tail. j-loop live set kept minimal
// (anchors + trackers only; sa/pv/vm recomputed or loaded in epilogue) so
// VGPR ~60 -> 8 waves/SIMD without any min-waves launch_bounds (r4's spill
// trap). Fast path (all gt labels == 0, __ballot-detected): division-free
// predicates iou>=0.5 <=> fma(inter,3,-ga) >= area_a+eps; iou<0.4 <=>
// fma(inter,3.5,-ga) < area_a+eps -> 13 VALU ops/pair, independent fmax
// chains. Slow path: exact cross-multiplication argmax.
//
// ws: 32 floats: [0..15] per-image loss sums, [16..31] per-image pos counts.

#define A_N 200000
#define B_N 16
#define G_N 32
#define APT 8
#define BLK 256
#define TILE (BLK * APT)                 // 2048
#define NBX ((A_N + TILE - 1) / TILE)    // 98

#define C_POS (0.25f * 0.69314718f)      // alpha * ln2   (log2 -> ln fold)
#define C_NEG (0.75f * 0.69314718f)      // (1-alpha) * ln2

__launch_bounds__(BLK)
__global__ void rnl_main(const float4* __restrict__ anchors,
                         const float* __restrict__ probs,
                         const float* __restrict__ y_true,
                         float* __restrict__ ws) {
    __shared__ float4 sbox[G_N];        // gt corners {x1,y1,x2,y2}
    __shared__ float  snga[G_N];        // -ga
    __shared__ float  sga[G_N];         // ga   (slow path)
    __shared__ float  slab[G_N];        // label (slow path)
    __shared__ float  sraw[G_N * 5];
    __shared__ int    sflag;

    const int b = blockIdx.y;
    const int t = threadIdx.x;

    if (t < G_N * 5) sraw[t] = y_true[b * (G_N * 5) + t];
    __syncthreads();
    if (t < 64) {                          // wave 0 builds gt table + flag
        float lb = 0.0f;
        if (t < G_N) {
            float cx = sraw[t * 5 + 0], cy = sraw[t * 5 + 1];
            float w  = sraw[t * 5 + 2], h  = sraw[t * 5 + 3];
            lb = sraw[t * 5 + 4];
            float x1 = cx - 0.5f * w, y1 = cy - 0.5f * h;
            float x2 = cx + 0.5f * w, y2 = cy + 0.5f * h;
            float ga = (x2 - x1) * (y2 - y1);
            sbox[t] = make_float4(x1, y1, x2, y2);
            snga[t] = -ga; sga[t] = ga; slab[t] = lb;
        }
        unsigned long long bal = __ballot(lb != 0.0f);
        if (t == 0) sflag = (bal == 0ULL) ? 1 : 0;
    }
    __syncthreads();

    const int base = blockIdx.x * TILE + t;
    const float lab0 = slab[0];

    float loss = 0.0f, cnt = 0.0f;

    // anchors resident in regs for the whole j-loop (32 VGPR)
    float ax[APT], ay[APT], az[APT], aw[APT];
    #pragma unroll
    for (int k = 0; k < APT; ++k) {
        int idx  = base + k * BLK;
        int idxc = idx < A_N ? idx : A_N - 1;
        float4 an = anchors[idxc];
        ax[k] = an.x; ay[k] = an.y; az[k] = an.z; aw[k] = an.w;
    }

    if (sflag) {
        // ---- fast path: all labels zero -> 13 ops/pair, fmax-chain trackers
        float m1[APT], m2[APT];
        #pragma unroll
        for (int k = 0; k < APT; ++k) { m1[k] = -1e30f; m2[k] = -1e30f; }

        #pragma unroll
        for (int j = 0; j < G_N; ++j) {
            float4 gb  = sbox[j];
            float  nga = snga[j];
            #pragma unroll
            for (int k = 0; k < APT; ++k) {
                float ltx = fmaxf(ax[k], gb.x);
                float lty = fmaxf(ay[k], gb.y);
                float rbx = fminf(az[k], gb.z);
                float rby = fminf(aw[k], gb.w);
                float iw  = fmaxf(rbx - ltx, 0.0f);
                float ih  = fmaxf(rby - lty, 0.0f);
                float inter = iw * ih;
                m1[k] = fmaxf(m1[k], fmaf(inter, 3.0f, nga));
                m2[k] = fmaxf(m2[k], fmaf(inter, 3.5f, nga));
            }
        }
        #pragma unroll
        for (int k = 0; k < APT; ++k) {
            int idx  = base + k * BLK;
            bool valid = idx < A_N;
            int idxc = valid ? idx : A_N - 1;
            float sa = (az[k] - ax[k]) * (aw[k] - ay[k]) + 1e-8f;
            bool pos = m1[k] >= sa;             // max iou >= 0.5
            bool neg = m2[k] <  sa;             // max iou <  0.4
            float p = __builtin_amdgcn_fmed3f(probs[b * A_N + idxc], 1e-7f, 1.0f - 1e-7f);
            float q = 1.0f - p;
            float x = pos ? p : q;              // label==0 -> pos implies target hit
            float w = pos ? C_POS * q * q : C_NEG * p * p;
            float l = w * (-__log2f(x));
            l = ((pos | neg) && valid) ? l : 0.0f;
            loss += l;
            cnt  += (pos && valid) ? 1.0f : 0.0f;
        }
    } else {
        // ---- slow path: exact argmax + label (general correctness)
        float bi[APT], bS[APT], bl[APT];
        #pragma unroll
        for (int k = 0; k < APT; ++k) {
            bi[k] = 0.0f; bS[k] = 1.0f; bl[k] = lab0;
        }

        #pragma unroll
        for (int j = 0; j < G_N; ++j) {
            float4 gb = sbox[j];
            float  ga = sga[j];
            float  lb = slab[j];
            #pragma unroll
            for (int k = 0; k < APT; ++k) {
                float ltx = fmaxf(ax[k], gb.x);
                float lty = fmaxf(ay[k], gb.y);
                float rbx = fminf(az[k], gb.z);
                float rby = fminf(aw[k], gb.w);
                float iw  = fmaxf(rbx - ltx, 0.0f);
                float ih  = fmaxf(rby - lty, 0.0f);
                float inter = iw * ih;
                float sa = (az[k] - ax[k]) * (aw[k] - ay[k]) + 1e-8f;
                float S  = sa + ga;
                // iou_j > iou_best <=> inter_j*S_best > inter_best*S_j
                bool better = inter * bS[k] > bi[k] * S;
                bi[k] = better ? inter : bi[k];
                bS[k] = better ? S     : bS[k];
                bl[k] = better ? lb    : bl[k];
            }
        }
        #pragma unroll
        for (int k = 0; k < APT; ++k) {
            int idx  = base + k * BLK;
            bool valid = idx < A_N;
            int idxc = valid ? idx : A_N - 1;
            bool pos = 3.0f * bi[k] >= bS[k];   // max iou >= 0.5
            bool neg = 3.5f * bi[k] <  bS[k];   // max iou <  0.4
            bool tp  = pos && (bl[k] == 0.0f);  // one_hot(assigned, C=1) hit
            float p = __builtin_amdgcn_fmed3f(probs[b * A_N + idxc], 1e-7f, 1.0f - 1e-7f);
            float q = 1.0f - p;
            float x = tp ? p : q;
            float w = tp ? C_POS * q * q : C_NEG * p * p;
            float l = w * (-__log2f(x));
            l = ((pos | neg) && valid) ? l : 0.0f;
            loss += l;
            cnt  += (pos && valid) ? 1.0f : 0.0f;
        }
    }

    // block reduction: wave shuffle, then cross-wave via LDS, 2 atomics/block
    #pragma unroll
    for (int off = 32; off > 0; off >>= 1) {
        loss += __shfl_down(loss, off);
        cnt  += __shfl_down(cnt, off);
    }
    __shared__ float s_l[4], s_c[4];
    int wid  = t >> 6;
    int lane = t & 63;
    if (lane == 0) { s_l[wid] = loss; s_c[wid] = cnt; }
    __syncthreads();
    if (t == 0) {
        atomicAdd(&ws[b],       s_l[0] + s_l[1] + s_l[2] + s_l[3]);
        atomicAdd(&ws[B_N + b], s_c[0] + s_c[1] + s_c[2] + s_c[3]);
    }
}

__global__ void rnl_final(const float* __restrict__ ws, float* __restrict__ out) {
    if (threadIdx.x == 0) {
        float s = 0.0f;
        #pragma unroll
        for (int b = 0; b < B_N; ++b) {
            s += ws[b] / fmaxf(ws[B_N + b], 1.0f);
        }
        out[0] = s * (1.0f / (float)B_N);
    }
}

extern "C" void kernel_launch(void* const* d_in, const int* in_sizes, int n_in,
                              void* d_out, int out_size, void* d_ws, size_t ws_size,
                              hipStream_t stream) {
    const float* y_true     = (const float*)d_in[0];
    const float* y_classifs = (const float*)d_in[1];
    // d_in[2] = y_regressions: unused by the loss
    const float* anchors    = (const float*)d_in[3];
    float* ws = (float*)d_ws;

    hipMemsetAsync(ws, 0, 2 * B_N * sizeof(float), stream);  // capturable memset node

    dim3 grid(NBX, B_N);
    rnl_main<<<grid, BLK, 0, stream>>>((const float4*)anchors, y_classifs,
                                       y_true, ws);

    rnl_final<<<1, 64, 0, stream>>>(ws, (float*)d_out);
}